// Round 15
// baseline (367.589 us; speedup 1.0000x reference)
//
#include <hip/hip_runtime.h>

// HierarchicalLTI2: 32-layer cascade of 64-dim LTI blocks, T=8192.
// R15 = R14 with host lambda replaced by explicit offsets (two container
// failures on identical source; lambda was the only never-tested construct).
// Device code byte-identical. Full OOB/hang/layout audit passed.
// Full composition: whole network is ONE matrix FIR u->y, built by a 5-level
// binary merge tree: P_AB = P_B conv P_A ; D_AB = D_A (+) D_B conv P_A.
// P keeps 32 taps, D keeps 48 (delays 1..48); dropped paths ~0.4^33.
// D-merges keep an f32 master for the copy-path (quantized once into ktd).
// Launches: prep | L1..L6 | ygemm (8 total; replaces 8 serial ~30us stages).

#define NO   64
#define TSEQ 8192
#define PADU 48
#define UR   (TSEQ+PADU)          // 8240 padded u rows
#define KY   3072                 // final GEMM K = 48 taps * 64

typedef _Float16 h16;
typedef _Float16 h16x8 __attribute__((ext_vector_type(8)));
typedef float    f32x4 __attribute__((ext_vector_type(4)));

#define MFMA16(a,b,c) __builtin_amdgcn_mfma_f32_16x16x32_f16((a),(b),(c),0,0,0)

// ---- prep_build -------------------------------------------------------------
// blocks 0..31: layer singles T^(l)_j = A^j B via MFMA chain (f16 ops, f32
//   LDS master), j=0..15 (delay j+1). Writes TN (natural) + TT (transposed).
// blocks 32..543: zero uq pad (48 rows), cast u -> uq, cast C -> ccast.
__global__ __launch_bounds__(256) void prep_build(
    const float* __restrict__ u, const float* __restrict__ B0,
    const float* __restrict__ Bl, const float* __restrict__ Cst,
    const float* __restrict__ Ast,
    h16* __restrict__ uq, h16* __restrict__ ccast,
    h16* __restrict__ TN, h16* __restrict__ TT)
{
    __shared__ __align__(16) h16   Ah[64*72];     //  9,216 B
    __shared__ __align__(16) h16   kT[64*72];     //  9,216 B (K^T f16)
    __shared__ __align__(16) float kf[64*68];     // 17,408 B (K f32 master)
    const int tid = threadIdx.x;

    if (blockIdx.x < 32) {
        const int layer = blockIdx.x;
        const float* k0 = (layer == 0) ? B0 : (Bl + (size_t)(layer-1)*4096);
        const float* Aw = Ast + (size_t)layer*4096;
        for (int e8 = tid; e8 < 512; e8 += 256) {
            int n = e8 >> 3, m0 = (e8 & 7) << 3;
            f32x4 a0 = *(const f32x4*)&Aw[n*64 + m0];
            f32x4 a1 = *(const f32x4*)&Aw[n*64 + m0 + 4];
            h16 ah[8];
            #pragma unroll
            for (int t = 0; t < 4; t++) { ah[t] = (h16)a0[t]; ah[4+t] = (h16)a1[t]; }
            *(int4*)&Ah[n*72 + m0] = *(int4*)&ah[0];
            *(f32x4*)&kf[n*68 + m0]     = *(const f32x4*)&k0[n*64 + m0];
            *(f32x4*)&kf[n*68 + m0 + 4] = *(const f32x4*)&k0[n*64 + m0 + 4];
        }
        __syncthreads();

        const int wv = tid >> 6, lane = tid & 63, r = lane & 15, q = lane >> 4;
        const h16x8 a0 = *(const h16x8*)&Ah[(wv*16 + r)*72 + q*8];
        const h16x8 a1 = *(const h16x8*)&Ah[(wv*16 + r)*72 + 32 + q*8];

        for (int j = 0; j < 16; j++) {
            if (j > 0) {
                f32x4 acc[4] = {};
                #pragma unroll
                for (int c = 0; c < 4; c++) {
                    h16x8 b0 = *(const h16x8*)&kT[(c*16 + r)*72 + q*8];
                    h16x8 b1 = *(const h16x8*)&kT[(c*16 + r)*72 + 32 + q*8];
                    acc[c] = MFMA16(a0, b0, acc[c]);
                    acc[c] = MFMA16(a1, b1, acc[c]);
                }
                #pragma unroll
                for (int c = 0; c < 4; c++)
                    #pragma unroll
                    for (int g4 = 0; g4 < 4; g4++)
                        kf[(wv*16 + q*4 + g4)*68 + c*16 + r] = acc[c][g4];
                __syncthreads();
            }
            size_t base = (size_t)(layer*16 + j)*4096;
            for (int e8 = tid; e8 < 512; e8 += 256) {
                int n = e8 >> 3, m0 = (e8 & 7) << 3;
                f32x4 v0 = *(const f32x4*)&kf[n*68 + m0];
                f32x4 v1 = *(const f32x4*)&kf[n*68 + m0 + 4];
                h16 o[8];
                #pragma unroll
                for (int t = 0; t < 4; t++) { o[t] = (h16)v0[t]; o[4+t] = (h16)v1[t]; }
                *(int4*)&TN[base + (size_t)n*64 + m0] = *(int4*)&o[0];
                #pragma unroll
                for (int t = 0; t < 8; t++)
                    kT[(m0 + t)*72 + n] = o[t];
                h16 o2[8];
                #pragma unroll
                for (int t = 0; t < 8; t++) o2[t] = (h16)kf[(m0 + t)*68 + n];
                *(int4*)&TT[base + (size_t)n*64 + m0] = *(int4*)&o2[0];
            }
            __syncthreads();
        }
        return;
    }

    // prep section (512 blocks), int4 units
    const int s1 = 384;          // uq pad: 48*64 h16
    const int s2 = 65536;        // u cast
    const int s3 = 16384;        // ccast
    const int total = s1 + s2 + s3;          // 82,304
    const int4 z4 = make_int4(0,0,0,0);
    for (int e0 = (blockIdx.x - 32)*256 + tid; e0 < total; e0 += 512*256) {
        int e = e0;
        if (e < s1) { *(int4*)&uq[e*8] = z4; continue; }
        e -= s1;
        if (e < s2) {
            int el = e*8;
            f32x4 f0 = *(const f32x4*)&u[el];
            f32x4 f1 = *(const f32x4*)&u[el+4];
            h16 ov[8];
            #pragma unroll
            for (int j = 0; j < 4; j++) { ov[j] = (h16)f0[j]; ov[4+j] = (h16)f1[j]; }
            *(int4*)&uq[PADU*NO + el] = *(int4*)&ov[0];
            continue;
        }
        e -= s2;
        int el = e*8;
        f32x4 f0 = *(const f32x4*)&Cst[el];
        f32x4 f1 = *(const f32x4*)&Cst[el+4];
        h16 ov[8];
        #pragma unroll
        for (int j = 0; j < 4; j++) { ov[j] = (h16)f0[j]; ov[4+j] = (h16)f1[j]; }
        *(int4*)&ccast[el] = *(int4*)&ov[0];
    }
}

// ---- compose core: acc += X(64x64 natural) * Y^T(stored [col][k]) ----------
__device__ __forceinline__ void comp_mm(const h16* __restrict__ X,
                                        const h16* __restrict__ Y,
                                        int wv, int r, int q, f32x4 acc[4])
{
    h16x8 a0 = *(const h16x8*)(X + (wv*16 + r)*64 + q*8);
    h16x8 a1 = *(const h16x8*)(X + (wv*16 + r)*64 + 32 + q*8);
    #pragma unroll
    for (int c = 0; c < 4; c++) {
        h16x8 b0 = *(const h16x8*)(Y + (c*16 + r)*64 + q*8);
        h16x8 b1 = *(const h16x8*)(Y + (c*16 + r)*64 + 32 + q*8);
        acc[c] = MFMA16(a0, b0, acc[c]);
        acc[c] = MFMA16(a1, b1, acc[c]);
    }
}
// C/D layout: element (row = wv*16 + q*4 + g4, col = c*16 + r).

__device__ __forceinline__ void conv_loop(const h16* X, const h16* Y, int n,
                                          int wv, int r, int q, f32x4 acc[4])
{
    for (int it = 0; it < n; ++it) {
        comp_mm(X, Y, wv, r, q, acc);
        X += 4096; Y -= 4096;
    }
}
__device__ __forceinline__ void add_copy(const float* __restrict__ DF,
                                         int wv, int r, int q, f32x4 acc[4])
{
    #pragma unroll
    for (int c = 0; c < 4; c++)
        #pragma unroll
        for (int g4 = 0; g4 < 4; g4++)
            acc[c][g4] += DF[(size_t)(wv*16 + q*4 + g4)*64 + c*16 + r];
}
__device__ __forceinline__ void write_N(h16* o, int wv, int r, int q, const f32x4 acc[4])
{
    #pragma unroll
    for (int c = 0; c < 4; c++)
        #pragma unroll
        for (int g4 = 0; g4 < 4; g4++)
            o[(size_t)(wv*16 + q*4 + g4)*64 + c*16 + r] = (h16)acc[c][g4];
}
__device__ __forceinline__ void write_T(h16* o, int wv, int r, int q, const f32x4 acc[4])
{
    #pragma unroll
    for (int c = 0; c < 4; c++)
        #pragma unroll
        for (int g4 = 0; g4 < 4; g4++)
            o[(size_t)(c*16 + r)*64 + wv*16 + q*4 + g4] = (h16)acc[c][g4];
}
__device__ __forceinline__ void write_F(float* o, int wv, int r, int q, const f32x4 acc[4])
{
    #pragma unroll
    for (int c = 0; c < 4; c++)
        #pragma unroll
        for (int g4 = 0; g4 < 4; g4++)
            o[(size_t)(wv*16 + q*4 + g4)*64 + c*16 + r] = acc[c][g4];
}
#define IMAX(a,b) ((a)>(b)?(a):(b))
#define IMIN(a,b) ((a)<(b)?(a):(b))

// ---- L1: P2 (16 pairs x 31 taps, delay m+2) + DS = C_l * T^l_j -------------
__global__ __launch_bounds__(256) void lvl1(
    const h16* __restrict__ TN, const h16* __restrict__ TT,
    const h16* __restrict__ cc,
    h16* __restrict__ P2N, h16* __restrict__ P2T,
    h16* __restrict__ DSN, float* __restrict__ DSF)
{
    const int tid = threadIdx.x, wv = tid>>6, lane = tid&63, r = lane&15, q = lane>>4;
    f32x4 acc[4] = {};
    int bid = blockIdx.x;
    if (bid < 496) {
        int p = bid / 31, m = bid % 31, D = m + 2;
        int j0 = IMAX(1, D-16), j1 = IMIN(16, D-1);
        conv_loop(TN + ((size_t)((2*p+1)*16 + j0-1))*4096,
                  TT + ((size_t)((2*p)*16 + D-j0-1))*4096, j1-j0+1, wv, r, q, acc);
        write_N(P2N + ((size_t)(p*31 + m))*4096, wv, r, q, acc);
        write_T(P2T + ((size_t)(p*31 + m))*4096, wv, r, q, acc);
    } else {
        int idx = bid - 496, l = idx >> 4, j = idx & 15;
        conv_loop(cc + (size_t)l*4096, TT + ((size_t)(l*16 + j))*4096, 1, wv, r, q, acc);
        write_N(DSN + ((size_t)(l*16 + j))*4096, wv, r, q, acc);
        write_F(DSF + ((size_t)(l*16 + j))*4096, wv, r, q, acc);
    }
}

// ---- L2: D2 (16 x 32, delay m+1) + P4 (8 x 32, delay m+4) ------------------
__global__ __launch_bounds__(256) void lvl2(
    const h16* __restrict__ DSN, const float* __restrict__ DSF,
    const h16* __restrict__ TT,
    const h16* __restrict__ P2N, const h16* __restrict__ P2T,
    h16* __restrict__ D2N, float* __restrict__ D2F,
    h16* __restrict__ P4N, h16* __restrict__ P4T)
{
    const int tid = threadIdx.x, wv = tid>>6, lane = tid&63, r = lane&15, q = lane>>4;
    f32x4 acc[4] = {};
    int bid = blockIdx.x;
    if (bid < 512) {
        int p = bid >> 5, m = bid & 31, D = m + 1;
        int j0 = IMAX(1, D-16), j1 = IMIN(16, D-1);
        if (j1 >= j0)
            conv_loop(DSN + ((size_t)((2*p+1)*16 + j0-1))*4096,
                      TT + ((size_t)((2*p)*16 + D-j0-1))*4096, j1-j0+1, wv, r, q, acc);
        if (D <= 16) add_copy(DSF + ((size_t)((2*p)*16 + D-1))*4096, wv, r, q, acc);
        write_N(D2N + ((size_t)(p*32 + m))*4096, wv, r, q, acc);
        write_F(D2F + ((size_t)(p*32 + m))*4096, wv, r, q, acc);
    } else {
        int idx = bid - 512, qd = idx >> 5, m = idx & 31, D = m + 4;
        int j0 = IMAX(2, D-32), j1 = IMIN(32, D-2);
        conv_loop(P2N + ((size_t)((2*qd+1)*31 + j0-2))*4096,
                  P2T + ((size_t)((2*qd)*31 + D-j0-2))*4096, j1-j0+1, wv, r, q, acc);
        write_N(P4N + ((size_t)(qd*32 + m))*4096, wv, r, q, acc);
        write_T(P4T + ((size_t)(qd*32 + m))*4096, wv, r, q, acc);
    }
}

// ---- L3: D4 (8 x 48) + P8 (4 x 32, delay m+8) ------------------------------
__global__ __launch_bounds__(256) void lvl3(
    const h16* __restrict__ D2N, const float* __restrict__ D2F,
    const h16* __restrict__ P2T,
    const h16* __restrict__ P4N, const h16* __restrict__ P4T,
    h16* __restrict__ D4N, float* __restrict__ D4F,
    h16* __restrict__ P8N, h16* __restrict__ P8T)
{
    const int tid = threadIdx.x, wv = tid>>6, lane = tid&63, r = lane&15, q = lane>>4;
    f32x4 acc[4] = {};
    int bid = blockIdx.x;
    if (bid < 384) {
        int qd = bid / 48, m = bid % 48, D = m + 1;
        int j0 = IMAX(1, D-32), j1 = IMIN(32, D-2);
        if (j1 >= j0)
            conv_loop(D2N + ((size_t)((2*qd+1)*32 + j0-1))*4096,
                      P2T + ((size_t)((2*qd)*31 + D-j0-2))*4096, j1-j0+1, wv, r, q, acc);
        if (D <= 32) add_copy(D2F + ((size_t)((2*qd)*32 + D-1))*4096, wv, r, q, acc);
        write_N(D4N + ((size_t)(qd*48 + m))*4096, wv, r, q, acc);
        write_F(D4F + ((size_t)(qd*48 + m))*4096, wv, r, q, acc);
    } else {
        int idx = bid - 384, o = idx >> 5, m = idx & 31, D = m + 8;
        int j0 = IMAX(4, D-35), j1 = IMIN(35, D-4);
        conv_loop(P4N + ((size_t)((2*o+1)*32 + j0-4))*4096,
                  P4T + ((size_t)((2*o)*32 + D-j0-4))*4096, j1-j0+1, wv, r, q, acc);
        write_N(P8N + ((size_t)(o*32 + m))*4096, wv, r, q, acc);
        write_T(P8T + ((size_t)(o*32 + m))*4096, wv, r, q, acc);
    }
}

// ---- L4: D8 (4 x 48) + P16 (1 x 32, delay m+16; transposed only) -----------
__global__ __launch_bounds__(256) void lvl4(
    const h16* __restrict__ D4N, const float* __restrict__ D4F,
    const h16* __restrict__ P4T,
    const h16* __restrict__ P8N, const h16* __restrict__ P8T,
    h16* __restrict__ D8N, float* __restrict__ D8F,
    h16* __restrict__ P16T)
{
    const int tid = threadIdx.x, wv = tid>>6, lane = tid&63, r = lane&15, q = lane>>4;
    f32x4 acc[4] = {};
    int bid = blockIdx.x;
    if (bid < 192) {
        int o = bid / 48, m = bid % 48, D = m + 1;
        int j0 = IMAX(1, D-35), j1 = IMIN(48, D-4);
        if (j1 >= j0)
            conv_loop(D4N + ((size_t)((2*o+1)*48 + j0-1))*4096,
                      P4T + ((size_t)((2*o)*32 + D-j0-4))*4096, j1-j0+1, wv, r, q, acc);
        add_copy(D4F + ((size_t)((2*o)*48 + D-1))*4096, wv, r, q, acc);
        write_N(D8N + ((size_t)(o*48 + m))*4096, wv, r, q, acc);
        write_F(D8F + ((size_t)(o*48 + m))*4096, wv, r, q, acc);
    } else {
        int m = bid - 192, D = m + 16;
        int j0 = IMAX(8, D-39), j1 = IMIN(39, D-8);
        conv_loop(P8N + ((size_t)(32 + j0-8))*4096,
                  P8T + ((size_t)(D-j0-8))*4096, j1-j0+1, wv, r, q, acc);
        write_T(P16T + (size_t)m*4096, wv, r, q, acc);
    }
}

// ---- L5: D16 (2 x 48) ------------------------------------------------------
__global__ __launch_bounds__(256) void lvl5(
    const h16* __restrict__ D8N, const float* __restrict__ D8F,
    const h16* __restrict__ P8T,
    h16* __restrict__ D16N, float* __restrict__ D16F)
{
    const int tid = threadIdx.x, wv = tid>>6, lane = tid&63, r = lane&15, q = lane>>4;
    f32x4 acc[4] = {};
    int h = blockIdx.x / 48, m = blockIdx.x % 48, D = m + 1;
    int j0 = IMAX(1, D-39), j1 = IMIN(48, D-8);
    if (j1 >= j0)
        conv_loop(D8N + ((size_t)((2*h+1)*48 + j0-1))*4096,
                  P8T + ((size_t)((2*h)*32 + D-j0-8))*4096, j1-j0+1, wv, r, q, acc);
    add_copy(D8F + ((size_t)((2*h)*48 + D-1))*4096, wv, r, q, acc);
    write_N(D16N + ((size_t)(h*48 + m))*4096, wv, r, q, acc);
    write_F(D16F + ((size_t)(h*48 + m))*4096, wv, r, q, acc);
}

// ---- L6: D32 (48 taps) -> ktd[y][(48-D)*64 + m] ----------------------------
__global__ __launch_bounds__(256) void lvl6(
    const h16* __restrict__ D16N, const float* __restrict__ D16F,
    const h16* __restrict__ P16T, h16* __restrict__ ktd)
{
    const int tid = threadIdx.x, wv = tid>>6, lane = tid&63, r = lane&15, q = lane>>4;
    f32x4 acc[4] = {};
    int m = blockIdx.x, D = m + 1;
    int j0 = IMAX(1, D-47), j1 = IMIN(48, D-16);
    if (j1 >= j0)
        conv_loop(D16N + ((size_t)(48 + j0-1))*4096,
                  P16T + ((size_t)(D-j0-16))*4096, j1-j0+1, wv, r, q, acc);
    add_copy(D16F + (size_t)m*4096, wv, r, q, acc);
    #pragma unroll
    for (int c = 0; c < 4; c++)
        #pragma unroll
        for (int g4 = 0; g4 < 4; g4++) {
            int y = wv*16 + q*4 + g4;
            ktd[(size_t)y*KY + (size_t)(48-D)*64 + c*16 + r] = (h16)acc[c][g4];
        }
}

// ---- ygemm: y = D_total * u. M=8192 (256 x 32-row blocks), N=64, K=3072 ----
// 8 waves, split-K8 (384 each = 6 tap-slots), 2-slot prefetch.
__global__ __launch_bounds__(512) void ygemm(
    const h16* __restrict__ uq, const h16* __restrict__ ktd,
    float* __restrict__ out)
{
    __shared__ __align__(16) h16   win[80*72];       // 11,520 B
    __shared__ __align__(16) float red[4*32*68];     // 34,816 B
    const int tid = threadIdx.x;
    const size_t t0 = (size_t)blockIdx.x * 32;

    for (int e = tid; e < 80*8; e += 512) {
        int rr = e >> 3, cc = e & 7;
        *(int4*)&win[rr*72 + cc*8] = *(const int4*)&uq[(t0 + rr)*64 + cc*8];
    }
    __syncthreads();

    const int wv = tid >> 6, lane = tid & 63, r = lane & 15, q = lane >> 4;
    const h16* abase = &win[(r + wv*6)*72 + q*8];
    const h16* bbase = ktd + (size_t)r*KY + wv*384 + q*8;
#define LDA(s, ls) (*(const h16x8*)(abase + ((s)*16 + ((ls)>>1))*72 + ((ls)&1)*32))
#define LDB(c, ls) (*(const h16x8*)(bbase + (size_t)(c)*(16*KY) + (ls)*32))
    f32x4 acc[2][4] = {};
    h16x8 a[2][2], b[2][4];
    #pragma unroll
    for (int sl = 0; sl < 2; sl++) {
        #pragma unroll
        for (int s = 0; s < 2; s++) a[sl][s] = LDA(s, sl);
        #pragma unroll
        for (int c = 0; c < 4; c++) b[sl][c] = LDB(c, sl);
    }
    #pragma unroll
    for (int ls = 0; ls < 12; ls++) {
        h16x8 ca[2], cb[4];
        #pragma unroll
        for (int s = 0; s < 2; s++) ca[s] = a[ls&1][s];
        #pragma unroll
        for (int c = 0; c < 4; c++) cb[c] = b[ls&1][c];
        if (ls < 10) {
            #pragma unroll
            for (int s = 0; s < 2; s++) a[ls&1][s] = LDA(s, ls+2);
            #pragma unroll
            for (int c = 0; c < 4; c++) b[ls&1][c] = LDB(c, ls+2);
        }
        #pragma unroll
        for (int s = 0; s < 2; s++)
            #pragma unroll
            for (int c = 0; c < 4; c++)
                acc[s][c] = MFMA16(ca[s], cb[c], acc[s][c]);
    }
#undef LDA
#undef LDB
    const int kq = wv & 3;
    const int rh = (wv >> 2) * (2*32*68);
    __syncthreads();
    if (kq >= 2) {
        float* myred = red + rh + (kq-2)*(32*68);
        #pragma unroll
        for (int s2 = 0; s2 < 2; s2++)
            #pragma unroll
            for (int c = 0; c < 4; c++)
                #pragma unroll
                for (int g4 = 0; g4 < 4; g4++)
                    myred[(s2*16 + q*4 + g4)*68 + c*16 + r] = acc[s2][c][g4];
    }
    __syncthreads();
    if (kq < 2) {
        float* myred = red + rh + kq*(32*68);
        #pragma unroll
        for (int s2 = 0; s2 < 2; s2++)
            #pragma unroll
            for (int c = 0; c < 4; c++)
                #pragma unroll
                for (int g4 = 0; g4 < 4; g4++)
                    myred[(s2*16 + q*4 + g4)*68 + c*16 + r] += acc[s2][c][g4];
    }
    __syncthreads();
    if (tid < 256) {
        int orow = tid >> 3, cb2 = (tid & 7) << 3;
        f32x4 u0 = *(const f32x4*)&red[orow*68 + cb2];
        f32x4 u1 = *(const f32x4*)&red[orow*68 + cb2 + 4];
        #pragma unroll
        for (int bnk = 1; bnk < 4; bnk++) {
            u0 += *(const f32x4*)&red[bnk*(32*68) + orow*68 + cb2];
            u1 += *(const f32x4*)&red[bnk*(32*68) + orow*68 + cb2 + 4];
        }
        size_t obase = (t0 + orow)*64 + cb2;
        *(f32x4*)&out[obase]     = u0;
        *(f32x4*)&out[obase + 4] = u1;
    }
}

extern "C" void kernel_launch(void* const* d_in, const int* in_sizes, int n_in,
                              void* d_out, int out_size, void* d_ws, size_t ws_size,
                              hipStream_t stream)
{
    const float* u   = (const float*)d_in[0];
    const float* Ast = (const float*)d_in[1];
    const float* B0  = (const float*)d_in[2];
    const float* Bl  = (const float*)d_in[3];
    const float* Cst = (const float*)d_in[4];
    float* out = (float*)d_out;
    (void)in_sizes; (void)n_in; (void)out_size; (void)ws_size;

    char* ws = (char*)d_ws;
    // explicit 512B-aligned offsets (total 66,459,648 B < ws_size)
    h16*   uq    = (h16*)  (ws + 0);          // 1,054,720
    h16*   ccast = (h16*)  (ws + 1054720);    //   262,144
    h16*   TN    = (h16*)  (ws + 1316864);    // 4,194,304
    h16*   TT    = (h16*)  (ws + 5511168);    // 4,194,304
    h16*   P2N   = (h16*)  (ws + 9705472);    // 4,063,232
    h16*   P2T   = (h16*)  (ws + 13768704);   // 4,063,232
    h16*   P4N   = (h16*)  (ws + 17831936);   // 2,097,152
    h16*   P4T   = (h16*)  (ws + 19929088);   // 2,097,152
    h16*   P8N   = (h16*)  (ws + 22026240);   // 1,048,576
    h16*   P8T   = (h16*)  (ws + 23074816);   // 1,048,576
    h16*   P16T  = (h16*)  (ws + 24123392);   //   262,144
    h16*   DSN   = (h16*)  (ws + 24385536);   // 4,194,304
    float* DSF   = (float*)(ws + 28579840);   // 8,388,608
    h16*   D2N   = (h16*)  (ws + 36968448);   // 4,194,304
    float* D2F   = (float*)(ws + 41162752);   // 8,388,608
    h16*   D4N   = (h16*)  (ws + 49551360);   // 3,145,728
    float* D4F   = (float*)(ws + 52697088);   // 6,291,456
    h16*   D8N   = (h16*)  (ws + 58988544);   // 1,572,864
    float* D8F   = (float*)(ws + 60561408);   // 3,145,728
    h16*   D16N  = (h16*)  (ws + 63707136);   //   786,432
    float* D16F  = (float*)(ws + 64493568);   // 1,572,864
    h16*   ktd   = (h16*)  (ws + 66066432);   //   393,216

    prep_build<<<544, 256, 0, stream>>>(u, B0, Bl, Cst, Ast, uq, ccast, TN, TT);
    lvl1<<<1008, 256, 0, stream>>>(TN, TT, ccast, P2N, P2T, DSN, DSF);
    lvl2<<<768, 256, 0, stream>>>(DSN, DSF, TT, P2N, P2T, D2N, D2F, P4N, P4T);
    lvl3<<<512, 256, 0, stream>>>(D2N, D2F, P2T, P4N, P4T, D4N, D4F, P8N, P8T);
    lvl4<<<224, 256, 0, stream>>>(D4N, D4F, P4T, P8N, P8T, D8N, D8F, P16T);
    lvl5<<<96, 256, 0, stream>>>(D8N, D8F, P8T, D16N, D16F);
    lvl6<<<48, 256, 0, stream>>>(D16N, D16F, P16T, ktd);
    ygemm<<<TSEQ/32, 512, 0, stream>>>(uq, ktd, out);
}

// Round 16
// 262.753 us; speedup vs baseline: 1.3990x; 1.3990x over previous
//
#include <hip/hip_runtime.h>

// HierarchicalLTI2: 32-layer cascade of 64-dim LTI blocks, T=8192.
// R16 = R13 (303us best) + ONE more merge level: quads -> 8-layer octet
// groups. P8 = Q_hi conv Q_lo (32 taps, delays 8..39); D8 = D4_lo (+)
// D4_hi conv Q_lo (32 taps). Stages 8 -> 4; stage kernel = R13's verified
// stage with a 104-row window (+1-row shift) and y-half abase+7 rows.
// R15 lesson: deep-tree D-merges (48-tap chains in <=512 blocks) crawl at
// 2% util (lvl3 = 71us) -- keep chains <=26 and heavy work in the stages.

#define NO   64
#define TSEQ 8192
#define PAD8 40
#define PRX  8240                 // padded rows per x buffer (8232 + slack)
#define PBX  ((size_t)PRX*NO)     // 527360 elems
#define KQ   2048                 // stage K = 32 taps * 64

typedef _Float16 h16;
typedef _Float16 h16x8 __attribute__((ext_vector_type(8)));
typedef float    f32x4 __attribute__((ext_vector_type(4)));

#define MFMA16(a,b,c) __builtin_amdgcn_mfma_f32_16x16x32_f16((a),(b),(c),0,0,0)
#define IMAX(a,b) ((a)>(b)?(a):(b))
#define IMIN(a,b) ((a)<(b)?(a):(b))

// ---- prep_build (R13 verified): layer singles via MFMA chain ----------------
// blocks 0..31: T^(l)_j = A^j B, j=0..15; SN (natural, l%4!=0), ST (transp,
// l%4==0). blocks 32..543: zero xq pads, cast u, cast C, zero Dacc.
__global__ __launch_bounds__(256) void prep_build(
    const float* __restrict__ u, const float* __restrict__ B0,
    const float* __restrict__ Bl, const float* __restrict__ Cst,
    const float* __restrict__ Ast,
    h16* __restrict__ xq, h16* __restrict__ ccast,
    h16* __restrict__ SN, h16* __restrict__ ST,
    float* __restrict__ Dacc)
{
    __shared__ __align__(16) h16   Ah[64*72];
    __shared__ __align__(16) h16   kT[64*72];
    __shared__ __align__(16) float kf[64*68];
    const int tid = threadIdx.x;

    if (blockIdx.x < 32) {
        const int layer = blockIdx.x;
        const bool wantST = (layer & 3) == 0;
        const float* k0 = (layer == 0) ? B0 : (Bl + (size_t)(layer-1)*4096);
        const float* Aw = Ast + (size_t)layer*4096;
        for (int e8 = tid; e8 < 512; e8 += 256) {
            int n = e8 >> 3, m0 = (e8 & 7) << 3;
            f32x4 a0 = *(const f32x4*)&Aw[n*64 + m0];
            f32x4 a1 = *(const f32x4*)&Aw[n*64 + m0 + 4];
            h16 ah[8];
            #pragma unroll
            for (int t = 0; t < 4; t++) { ah[t] = (h16)a0[t]; ah[4+t] = (h16)a1[t]; }
            *(int4*)&Ah[n*72 + m0] = *(int4*)&ah[0];
            *(f32x4*)&kf[n*68 + m0]     = *(const f32x4*)&k0[n*64 + m0];
            *(f32x4*)&kf[n*68 + m0 + 4] = *(const f32x4*)&k0[n*64 + m0 + 4];
        }
        __syncthreads();
        const int wv = tid >> 6, lane = tid & 63, r = lane & 15, q = lane >> 4;
        const h16x8 a0 = *(const h16x8*)&Ah[(wv*16 + r)*72 + q*8];
        const h16x8 a1 = *(const h16x8*)&Ah[(wv*16 + r)*72 + 32 + q*8];
        for (int j = 0; j < 16; j++) {
            if (j > 0) {
                f32x4 acc[4] = {};
                #pragma unroll
                for (int c = 0; c < 4; c++) {
                    h16x8 b0 = *(const h16x8*)&kT[(c*16 + r)*72 + q*8];
                    h16x8 b1 = *(const h16x8*)&kT[(c*16 + r)*72 + 32 + q*8];
                    acc[c] = MFMA16(a0, b0, acc[c]);
                    acc[c] = MFMA16(a1, b1, acc[c]);
                }
                #pragma unroll
                for (int c = 0; c < 4; c++)
                    #pragma unroll
                    for (int g4 = 0; g4 < 4; g4++)
                        kf[(wv*16 + q*4 + g4)*68 + c*16 + r] = acc[c][g4];
                __syncthreads();
            }
            size_t base = (size_t)(layer*16 + j)*4096;
            for (int e8 = tid; e8 < 512; e8 += 256) {
                int n = e8 >> 3, m0 = (e8 & 7) << 3;
                f32x4 v0 = *(const f32x4*)&kf[n*68 + m0];
                f32x4 v1 = *(const f32x4*)&kf[n*68 + m0 + 4];
                h16 o[8];
                #pragma unroll
                for (int t = 0; t < 4; t++) { o[t] = (h16)v0[t]; o[4+t] = (h16)v1[t]; }
                if (!wantST)
                    *(int4*)&SN[base + (size_t)n*64 + m0] = *(int4*)&o[0];
                #pragma unroll
                for (int t = 0; t < 8; t++)
                    kT[(m0 + t)*72 + n] = o[t];
                if (wantST) {
                    h16 o2[8];
                    #pragma unroll
                    for (int t = 0; t < 8; t++) o2[t] = (h16)kf[(m0 + t)*68 + n];
                    *(int4*)&ST[base + (size_t)n*64 + m0] = *(int4*)&o2[0];
                }
            }
            __syncthreads();
        }
        return;
    }

    // prep section (512 blocks), int4 units
    const int s1 = 320;          // xq[0] pad: 40*64 h16
    const int s2 = 65536;        // u cast
    const int s3 = 960;          // xq[1..3] pads: 3 * 320
    const int s4 = 16384;        // ccast
    const int s6 = 262144;       // Dacc zero (4,194,304 B)
    const int total = s1+s2+s3+s4+s6;    // 345,344
    const int4 z4 = make_int4(0,0,0,0);
    for (int e0 = (blockIdx.x - 32)*256 + tid; e0 < total; e0 += 512*256) {
        int e = e0;
        if (e < s1) { *(int4*)&xq[e*8] = z4; continue; }
        e -= s1;
        if (e < s2) {
            int el = e*8;
            f32x4 f0 = *(const f32x4*)&u[el];
            f32x4 f1 = *(const f32x4*)&u[el+4];
            h16 ov[8];
            #pragma unroll
            for (int j = 0; j < 4; j++) { ov[j] = (h16)f0[j]; ov[4+j] = (h16)f1[j]; }
            *(int4*)&xq[PAD8*NO + el] = *(int4*)&ov[0];
            continue;
        }
        e -= s2;
        if (e < s3) {
            int b = e / 320, off = (e % 320)*8;
            *(int4*)&xq[(size_t)(b+1)*PBX + off] = z4;
            continue;
        }
        e -= s3;
        if (e < s4) {
            int el = e*8;
            f32x4 f0 = *(const f32x4*)&Cst[el];
            f32x4 f1 = *(const f32x4*)&Cst[el+4];
            h16 ov[8];
            #pragma unroll
            for (int j = 0; j < 4; j++) { ov[j] = (h16)f0[j]; ov[4+j] = (h16)f1[j]; }
            *(int4*)&ccast[el] = *(int4*)&ov[0];
            continue;
        }
        e -= s4;
        *(int4*)&Dacc[e*4] = z4;
    }
}

// ---- compose helpers (R13 verified) ----------------------------------------
__device__ __forceinline__ void comp_mm(const h16* __restrict__ X,
                                        const h16* __restrict__ Y,
                                        int wv, int r, int q, f32x4 acc[4])
{
    h16x8 a0 = *(const h16x8*)(X + (wv*16 + r)*64 + q*8);
    h16x8 a1 = *(const h16x8*)(X + (wv*16 + r)*64 + 32 + q*8);
    #pragma unroll
    for (int c = 0; c < 4; c++) {
        h16x8 b0 = *(const h16x8*)(Y + (c*16 + r)*64 + q*8);
        h16x8 b1 = *(const h16x8*)(Y + (c*16 + r)*64 + 32 + q*8);
        acc[c] = MFMA16(a0, b0, acc[c]);
        acc[c] = MFMA16(a1, b1, acc[c]);
    }
}
// C/D layout: row = wv*16 + q*4 + g4, col = c*16 + r.
__device__ __forceinline__ void conv_loop(const h16* X, const h16* Y, int n,
                                          int wv, int r, int q, f32x4 acc[4])
{
    for (int it = 0; it < n; ++it) {
        comp_mm(X, Y, wv, r, q, acc);
        X += 4096; Y -= 4096;
    }
}
__device__ __forceinline__ void write_N(h16* o, int wv, int r, int q, const f32x4 acc[4])
{
    #pragma unroll
    for (int c = 0; c < 4; c++)
        #pragma unroll
        for (int g4 = 0; g4 < 4; g4++)
            o[(size_t)(wv*16 + q*4 + g4)*64 + c*16 + r] = (h16)acc[c][g4];
}
__device__ __forceinline__ void write_T(h16* o, int wv, int r, int q, const f32x4 acc[4])
{
    #pragma unroll
    for (int c = 0; c < 4; c++)
        #pragma unroll
        for (int g4 = 0; g4 < 4; g4++)
            o[(size_t)(c*16 + r)*64 + wv*16 + q*4 + g4] = (h16)acc[c][g4];
}

// ---- compose2: P2T[g][m2] = (T^{4g+1} conv T^{4g})^T, m2=0..30 (D=m2+2) ----
// plus D1: Dacc[g][j] += C_{4g} * T^{4g}_j, j=0..15.
__global__ __launch_bounds__(256) void compose2(
    const h16* __restrict__ SN, const h16* __restrict__ ST,
    const h16* __restrict__ cc, h16* __restrict__ P2T,
    float* __restrict__ Dacc)
{
    const int tid = threadIdx.x, wv = tid>>6, lane = tid&63, r = lane&15, q = lane>>4;
    f32x4 acc[4] = {};
    int bid = blockIdx.x;
    if (bid < 248) {
        int g = bid / 31, m2 = bid % 31;
        int j0 = IMAX(0, m2 - 15);
        int j1 = IMIN(15, m2);
        conv_loop(SN + ((size_t)((4*g+1)*16) + j0)*4096,
                  ST + ((size_t)((4*g)*16) + (m2 - j0))*4096, j1-j0+1, wv, r, q, acc);
        write_T(P2T + ((size_t)(g*31 + m2))*4096, wv, r, q, acc);
    } else {
        int idx = bid - 248, g = idx >> 4, j = idx & 15;
        comp_mm(cc + (size_t)(4*g)*4096, ST + ((size_t)((4*g)*16) + j)*4096, wv, r, q, acc);
        float* Dd = Dacc + ((size_t)(g*32 + j))*4096;
        #pragma unroll
        for (int c = 0; c < 4; c++)
            #pragma unroll
            for (int g4 = 0; g4 < 4; g4++)
                atomicAdd(&Dd[(wv*16 + q*4 + g4)*64 + c*16 + r], acc[c][g4]);
    }
}

// ---- compose3: P3T[g][m3] = (T^{4g+2} conv P2)^T, m3=0..29 (D=m3+3) --------
// plus D2: Dacc[g][m2+1] += C_{4g+1} * P2_{m2}.
__global__ __launch_bounds__(256) void compose3(
    const h16* __restrict__ SN, const h16* __restrict__ cc,
    const h16* __restrict__ P2T, h16* __restrict__ P3T,
    float* __restrict__ Dacc)
{
    const int tid = threadIdx.x, wv = tid>>6, lane = tid&63, r = lane&15, q = lane>>4;
    f32x4 acc[4] = {};
    int bid = blockIdx.x;
    if (bid < 240) {
        int g = bid / 30, m3 = bid % 30;
        int j1 = IMIN(15, m3);
        conv_loop(SN + ((size_t)((4*g+2)*16))*4096,
                  P2T + ((size_t)(g*31 + m3))*4096, j1+1, wv, r, q, acc);
        write_T(P3T + ((size_t)(g*30 + m3))*4096, wv, r, q, acc);
    } else {
        int idx = bid - 240, g = idx / 31, m2 = idx % 31;
        comp_mm(cc + (size_t)(4*g+1)*4096, P2T + ((size_t)(g*31 + m2))*4096, wv, r, q, acc);
        float* Dd = Dacc + ((size_t)(g*32 + m2 + 1))*4096;
        #pragma unroll
        for (int c = 0; c < 4; c++)
            #pragma unroll
            for (int g4 = 0; g4 < 4; g4++)
                atomicAdd(&Dd[(wv*16 + q*4 + g4)*64 + c*16 + r], acc[c][g4]);
    }
}

// ---- compose4: Q[g]_{m4} (quad kernel, D=m4+4) -> P4N/P4T slices -----------
// also D4: Dacc[g][m4+3] += C_{4g+3}*Q_{m4} (LDS transpose);
// plus D3: Dacc[g][m3+2] += C_{4g+2} * P3_{m3}.
__global__ __launch_bounds__(256) void compose4(
    const h16* __restrict__ SN, const h16* __restrict__ cc,
    const h16* __restrict__ P3T,
    h16* __restrict__ P4N, h16* __restrict__ P4T,
    float* __restrict__ Dacc)
{
    __shared__ h16 ldsT[64*72];
    const int tid = threadIdx.x, wv = tid>>6, lane = tid&63, r = lane&15, q = lane>>4;
    f32x4 acc[4] = {};
    int bid = blockIdx.x;
    if (bid < 232) {
        int g = bid / 29, m4 = bid % 29;
        int j1 = IMIN(15, m4);
        conv_loop(SN + ((size_t)((4*g+3)*16))*4096,
                  P3T + ((size_t)(g*30 + m4))*4096, j1+1, wv, r, q, acc);
        write_N(P4N + ((size_t)(g*29 + m4))*4096, wv, r, q, acc);
        write_T(P4T + ((size_t)(g*29 + m4))*4096, wv, r, q, acc);
        #pragma unroll
        for (int c = 0; c < 4; c++)
            #pragma unroll
            for (int g4 = 0; g4 < 4; g4++)
                ldsT[(c*16+r)*72 + wv*16 + q*4 + g4] = (h16)acc[c][g4];
        __syncthreads();
        f32x4 acc2[4] = {};
        const h16* Xc = cc + (size_t)(4*g+3)*4096;
        h16x8 a0 = *(const h16x8*)(Xc + (wv*16 + r)*64 + q*8);
        h16x8 a1 = *(const h16x8*)(Xc + (wv*16 + r)*64 + 32 + q*8);
        #pragma unroll
        for (int c = 0; c < 4; c++) {
            h16x8 b0 = *(const h16x8*)(&ldsT[(c*16+r)*72 + q*8]);
            h16x8 b1 = *(const h16x8*)(&ldsT[(c*16+r)*72 + 32 + q*8]);
            acc2[c] = MFMA16(a0, b0, acc2[c]);
            acc2[c] = MFMA16(a1, b1, acc2[c]);
        }
        float* Dd = Dacc + ((size_t)(g*32 + m4 + 3))*4096;
        #pragma unroll
        for (int c = 0; c < 4; c++)
            #pragma unroll
            for (int g4 = 0; g4 < 4; g4++)
                atomicAdd(&Dd[(wv*16 + q*4 + g4)*64 + c*16 + r], acc2[c][g4]);
    } else {
        int idx = bid - 232, g = idx / 30, m3 = idx % 30;
        comp_mm(cc + (size_t)(4*g+2)*4096, P3T + ((size_t)(g*30 + m3))*4096, wv, r, q, acc);
        float* Dd = Dacc + ((size_t)(g*32 + m3 + 2))*4096;
        #pragma unroll
        for (int c = 0; c < 4; c++)
            #pragma unroll
            for (int g4 = 0; g4 < 4; g4++)
                atomicAdd(&Dd[(wv*16 + q*4 + g4)*64 + c*16 + r], acc[c][g4]);
    }
}

// ---- castD: Dacc f32 -> D4N f16 (plain elementwise, same layout) -----------
__global__ __launch_bounds__(256) void castD(const float* __restrict__ Dacc,
                                             h16* __restrict__ D4N)
{
    const int total4 = 8*32*4096/4;     // 262,144
    for (int idx4 = blockIdx.x*256 + threadIdx.x; idx4 < total4; idx4 += 256*256) {
        int idx = idx4 << 2;
        f32x4 f = *(const f32x4*)&Dacc[idx];
        h16 o4[4];
        #pragma unroll
        for (int t = 0; t < 4; t++) o4[t] = (h16)f[t];
        *(int2*)&D4N[idx] = *(int2*)&o4[0];
    }
}

// ---- compose5: octet merges -> stage layouts -------------------------------
// bid<128: P8[o]_D = sum_j Q^{2o+1}_j Q^{2o}_{D-j}, D=m+8 in [8,39],
//   j,D-j in [4,32] -> ktq8[o][n][(39-D)*64+m'].
// bid>=128: D8[o]_D = D4F[2o]_D + sum_{j=1}^{D-4} D4N^{2o+1}_j Q^{2o,T}_{D-j},
//   D=m+1 in [1,32] -> ktd8[o][y][(32-D)*64+m'].
__global__ __launch_bounds__(256) void compose5(
    const h16* __restrict__ P4N, const h16* __restrict__ P4T,
    const h16* __restrict__ D4N, const float* __restrict__ D4F,
    h16* __restrict__ ktq8, h16* __restrict__ ktd8)
{
    const int tid = threadIdx.x, wv = tid>>6, lane = tid&63, r = lane&15, q = lane>>4;
    f32x4 acc[4] = {};
    int bid = blockIdx.x;
    if (bid < 128) {
        int o = bid >> 5, m = bid & 31, D = m + 8;
        int j0 = IMAX(4, D-32), j1 = IMIN(32, D-4);
        conv_loop(P4N + ((size_t)((2*o+1)*29) + (j0-4))*4096,
                  P4T + ((size_t)((2*o)*29) + (D-j0-4))*4096, j1-j0+1, wv, r, q, acc);
        h16* kq = ktq8 + (size_t)o*131072 + (size_t)(39 - D)*64;
        #pragma unroll
        for (int c = 0; c < 4; c++)
            #pragma unroll
            for (int g4 = 0; g4 < 4; g4++)
                kq[(size_t)(wv*16 + q*4 + g4)*KQ + c*16 + r] = (h16)acc[c][g4];
    } else {
        int idx = bid - 128, o = idx >> 5, m = idx & 31, D = m + 1;
        int n = D - 4;
        if (n > 0)
            conv_loop(D4N + ((size_t)((2*o+1)*32))*4096,
                      P4T + ((size_t)((2*o)*29) + (D-1-4))*4096, n, wv, r, q, acc);
        const float* DF = D4F + ((size_t)((2*o)*32 + D-1))*4096;
        #pragma unroll
        for (int c = 0; c < 4; c++)
            #pragma unroll
            for (int g4 = 0; g4 < 4; g4++)
                acc[c][g4] += DF[(size_t)(wv*16 + q*4 + g4)*64 + c*16 + r];
        h16* kd = ktd8 + (size_t)o*131072 + (size_t)(32 - D)*64;
        #pragma unroll
        for (int c = 0; c < 4; c++)
            #pragma unroll
            for (int g4 = 0; g4 < 4; g4++)
                kd[(size_t)(wv*16 + q*4 + g4)*KQ + c*16 + r] = (h16)acc[c][g4];
    }
}

// ---- stage8: one octet. M=64/block (2 sub-tiles sharing B), grid 128 -------
// waves 0-3: state (ktq8, delays 8..39); waves 4-7: y (ktd8, delays 1..32,
// abase shifted +7 rows). Window: 104 rows = padded t0+1 .. t0+104.
template<int WRST>
__global__ __launch_bounds__(512) void stage8(
    const h16* __restrict__ pin, h16* __restrict__ pout,
    const h16* __restrict__ ktqg, const h16* __restrict__ ktdg,
    float* __restrict__ out, int first)
{
    __shared__ __align__(16) h16   win[104*72];      // 14,976 B
    __shared__ __align__(16) float red[4*32*68];     // 34,816 B
    const int tid = threadIdx.x;
    const size_t t0 = (size_t)blockIdx.x * 64;

    for (int e = tid; e < 104*8; e += 512) {
        int rr = e >> 3, cc = e & 7;
        *(int4*)&win[rr*72 + cc*8] = *(const int4*)&pin[(t0 + 1 + rr)*64 + cc*8];
    }
    __syncthreads();

    const int wv = tid >> 6, lane = tid & 63, r = lane & 15, q = lane >> 4;
    const int half = wv >> 2, kq = wv & 3;
    const bool active = WRST || (half == 1);
    f32x4 acc[2][2][4] = {};                  // [sub-tile][s][c]
    if (active) {
        const h16* kb = half ? ktdg : ktqg;
        const h16* abase = &win[(r + kq*8 + (half ? 7 : 0))*72 + q*8];
        const h16* bbase = kb + (size_t)r*KQ + kq*512 + q*8;
#define LDA(st, s, ls) (*(const h16x8*)(abase + ((st)*32 + (s)*16 + ((ls)>>1))*72 + ((ls)&1)*32))
#define LDB(c, ls) (*(const h16x8*)(bbase + (size_t)(c)*(16*KQ) + (ls)*32))
        h16x8 a[2][2][2], b[2][4];            // a[slot][st][s], b[slot][c]
        #pragma unroll
        for (int sl = 0; sl < 2; sl++) {
            #pragma unroll
            for (int st = 0; st < 2; st++)
                #pragma unroll
                for (int s = 0; s < 2; s++) a[sl][st][s] = LDA(st, s, sl);
            #pragma unroll
            for (int c = 0; c < 4; c++) b[sl][c] = LDB(c, sl);
        }
        #pragma unroll
        for (int ls = 0; ls < 16; ls++) {
            h16x8 ca[2][2], cb[4];
            #pragma unroll
            for (int st = 0; st < 2; st++)
                #pragma unroll
                for (int s = 0; s < 2; s++) ca[st][s] = a[ls&1][st][s];
            #pragma unroll
            for (int c = 0; c < 4; c++) cb[c] = b[ls&1][c];
            if (ls < 14) {
                #pragma unroll
                for (int st = 0; st < 2; st++)
                    #pragma unroll
                    for (int s = 0; s < 2; s++) a[ls&1][st][s] = LDA(st, s, ls+2);
                #pragma unroll
                for (int c = 0; c < 4; c++) b[ls&1][c] = LDB(c, ls+2);
            }
            #pragma unroll
            for (int st = 0; st < 2; st++)
                #pragma unroll
                for (int s = 0; s < 2; s++)
                    #pragma unroll
                    for (int c = 0; c < 4; c++)
                        acc[st][s][c] = MFMA16(ca[st][s], cb[c], acc[st][s][c]);
        }
#undef LDA
#undef LDB
    }

    const int rh = half * (2*32*68);
    #pragma unroll
    for (int st = 0; st < 2; st++) {
        __syncthreads();
        if (active && kq >= 2) {
            float* myred = red + rh + (kq-2)*(32*68);
            #pragma unroll
            for (int s2 = 0; s2 < 2; s2++)
                #pragma unroll
                for (int c = 0; c < 4; c++)
                    #pragma unroll
                    for (int g4 = 0; g4 < 4; g4++)
                        myred[(s2*16 + q*4 + g4)*68 + c*16 + r] = acc[st][s2][c][g4];
        }
        __syncthreads();
        if (active && kq < 2) {
            float* myred = red + rh + kq*(32*68);
            #pragma unroll
            for (int s2 = 0; s2 < 2; s2++)
                #pragma unroll
                for (int c = 0; c < 4; c++)
                    #pragma unroll
                    for (int g4 = 0; g4 < 4; g4++)
                        myred[(s2*16 + q*4 + g4)*68 + c*16 + r] += acc[st][s2][c][g4];
        }
        __syncthreads();
        if (WRST && tid < 256) {
            int orow = tid >> 3, cb2 = (tid & 7) << 3;
            f32x4 u0 = *(const f32x4*)&red[orow*68 + cb2];
            f32x4 u1 = *(const f32x4*)&red[orow*68 + cb2 + 4];
            f32x4 v0 = *(const f32x4*)&red[32*68 + orow*68 + cb2];
            f32x4 v1 = *(const f32x4*)&red[32*68 + orow*68 + cb2 + 4];
            u0 += v0; u1 += v1;
            h16 ov[8];
            #pragma unroll
            for (int j = 0; j < 4; j++) { ov[j] = (h16)u0[j]; ov[4+j] = (h16)u1[j]; }
            *(int4*)&pout[(PAD8 + t0 + st*32 + orow)*64 + cb2] = *(int4*)&ov[0];
        }
        if (tid >= 256) {
            int t2 = tid - 256;
            int orow = t2 >> 3, cb2 = (t2 & 7) << 3;
            const float* base = red + 2*32*68;
            f32x4 u0 = *(const f32x4*)&base[orow*68 + cb2];
            f32x4 u1 = *(const f32x4*)&base[orow*68 + cb2 + 4];
            f32x4 v0 = *(const f32x4*)&base[32*68 + orow*68 + cb2];
            f32x4 v1 = *(const f32x4*)&base[32*68 + orow*68 + cb2 + 4];
            u0 += v0; u1 += v1;
            float* op = out + (t0 + st*32 + orow)*64 + cb2;
            if (first) {
                *(f32x4*)op = u0; *(f32x4*)(op+4) = u1;
            } else {
                f32x4 o0 = *(f32x4*)op, o1 = *(f32x4*)(op+4);
                o0 += u0; o1 += u1;
                *(f32x4*)op = o0; *(f32x4*)(op+4) = o1;
            }
        }
    }
}

extern "C" void kernel_launch(void* const* d_in, const int* in_sizes, int n_in,
                              void* d_out, int out_size, void* d_ws, size_t ws_size,
                              hipStream_t stream)
{
    const float* u   = (const float*)d_in[0];
    const float* Ast = (const float*)d_in[1];
    const float* B0  = (const float*)d_in[2];
    const float* Bl  = (const float*)d_in[3];
    const float* Cst = (const float*)d_in[4];
    float* out = (float*)d_out;
    (void)in_sizes; (void)n_in; (void)out_size; (void)ws_size;

    char* ws = (char*)d_ws;
    h16*   xq   = (h16*)  (ws + 0);          // 4 x 1,054,720 = 4,218,880
    h16*   ccast= (h16*)  (ws + 4218880);    //   262,144
    h16*   SN   = (h16*)  (ws + 4481024);    // 4,194,304
    h16*   ST   = (h16*)  (ws + 8675328);    // 4,194,304
    h16*   P2T  = (h16*)  (ws + 12869632);   // 2,031,616
    h16*   P3T  = (h16*)  (ws + 14901248);   // 1,966,080
    h16*   P4N  = (h16*)  (ws + 16867328);   // 1,900,544
    h16*   P4T  = (h16*)  (ws + 18767872);   // 1,900,544
    float* Dacc = (float*)(ws + 20668416);   // 4,194,304
    h16*   D4N  = (h16*)  (ws + 24862720);   // 2,097,152
    h16*   ktq8 = (h16*)  (ws + 26959872);   // 1,048,576
    h16*   ktd8 = (h16*)  (ws + 28008448);   // 1,048,576

    prep_build<<<544, 256, 0, stream>>>(u, B0, Bl, Cst, Ast, xq, ccast, SN, ST, Dacc);
    compose2<<<376, 256, 0, stream>>>(SN, ST, ccast, P2T, Dacc);
    compose3<<<488, 256, 0, stream>>>(SN, ccast, P2T, P3T, Dacc);
    compose4<<<472, 256, 0, stream>>>(SN, ccast, P3T, P4N, P4T, Dacc);
    castD<<<256, 256, 0, stream>>>(Dacc, D4N);
    compose5<<<256, 256, 0, stream>>>(P4N, P4T, D4N, Dacc, ktq8, ktd8);
    for (int g = 0; g < 3; g++) {
        stage8<1><<<TSEQ/64, 512, 0, stream>>>(xq + (size_t)g*PBX, xq + (size_t)(g+1)*PBX,
                                               ktq8 + (size_t)g*131072, ktd8 + (size_t)g*131072,
                                               out, g == 0);
    }
    stage8<0><<<TSEQ/64, 512, 0, stream>>>(xq + (size_t)3*PBX, xq,
                                           ktq8 + (size_t)3*131072, ktd8 + (size_t)3*131072,
                                           out, 0);
}